// Round 4
// baseline (642.254 us; speedup 1.0000x reference)
//
#include <hip/hip_runtime.h>
#include <hip/hip_bf16.h>
#include <math.h>

#define N_NODES 50000
#define N_EDGES 800000
#define HEADS 4
#define NEG 0.2f

// ---------- GEMM (FOUT=128): out[N,128] = h[N,FIN] @ W[FIN,128] ----------
// 32 rows x 128 cols per block, 256 threads; thread = 4 rows x 4 cols.
// Per k: 4 LDS broadcast reads + 1 float4 W load + 16 FMAs (1:4 LDS:FMA).
template<int FIN>
__global__ __launch_bounds__(256) void gemm128_kernel(const float* __restrict__ h,
                                                      const float* __restrict__ W,
                                                      float* __restrict__ out) {
    constexpr int ROWS = 32;
    __shared__ float hs[ROWS][FIN];
    const int tid = threadIdx.x;
    const int rbase = blockIdx.x * ROWS;
    constexpr int VECS = ROWS * FIN / 4;
    for (int i = tid; i < VECS; i += 256) {
        int r = (i * 4) / FIN, c = (i * 4) % FIN;
        int gr = rbase + r;
        float4 v = {0.f, 0.f, 0.f, 0.f};
        if (gr < N_NODES) v = *(const float4*)(h + (size_t)gr * FIN + c);
        *(float4*)(&hs[r][c]) = v;
    }
    __syncthreads();
    const int c4 = (tid & 31) * 4;
    const int r0 = (tid >> 5) * 4;
    float a0[4] = {}, a1[4] = {}, a2[4] = {}, a3[4] = {};
    for (int k = 0; k < FIN; ++k) {
        const float4 w = *(const float4*)(W + k * 128 + c4);
        const float h0 = hs[r0 + 0][k], h1 = hs[r0 + 1][k];
        const float h2 = hs[r0 + 2][k], h3 = hs[r0 + 3][k];
        a0[0] += h0 * w.x; a0[1] += h0 * w.y; a0[2] += h0 * w.z; a0[3] += h0 * w.w;
        a1[0] += h1 * w.x; a1[1] += h1 * w.y; a1[2] += h1 * w.z; a1[3] += h1 * w.w;
        a2[0] += h2 * w.x; a2[1] += h2 * w.y; a2[2] += h2 * w.z; a2[3] += h2 * w.w;
        a3[0] += h3 * w.x; a3[1] += h3 * w.y; a3[2] += h3 * w.z; a3[3] += h3 * w.w;
    }
    float* rows[4] = {a0, a1, a2, a3};
#pragma unroll
    for (int i = 0; i < 4; ++i) {
        int gr = rbase + r0 + i;
        if (gr < N_NODES) {
            float4 v = {rows[i][0], rows[i][1], rows[i][2], rows[i][3]};
            *(float4*)(out + (size_t)gr * 128 + c4) = v;
        }
    }
}

// ---------- GEMM generic (used for FOUT=32 final layer) ----------
template<int FIN, int FOUT>
__global__ __launch_bounds__(128) void gemm_kernel(const float* __restrict__ h,
                                                   const float* __restrict__ W,
                                                   float* __restrict__ out) {
    constexpr int ROWS = 16;
    constexpr int SUBS = 128 / FOUT;
    constexpr int RPT  = ROWS / SUBS;
    __shared__ float hs[ROWS][FIN];
    const int tid = threadIdx.x;
    const int rbase = blockIdx.x * ROWS;
    for (int i = tid; i < ROWS * FIN; i += 128) {
        int r = i / FIN, c = i % FIN;
        int gr = rbase + r;
        hs[r][c] = (gr < N_NODES) ? h[(size_t)gr * FIN + c] : 0.f;
    }
    __syncthreads();
    const int col = tid % FOUT;
    const int sub = tid / FOUT;
    float acc[RPT];
#pragma unroll
    for (int i = 0; i < RPT; ++i) acc[i] = 0.f;
    for (int k = 0; k < FIN; ++k) {
        float w = W[k * FOUT + col];
#pragma unroll
        for (int i = 0; i < RPT; ++i) acc[i] += hs[sub * RPT + i][k] * w;
    }
#pragma unroll
    for (int i = 0; i < RPT; ++i) {
        int gr = rbase + sub * RPT + i;
        if (gr < N_NODES) out[(size_t)gr * FOUT + col] = acc[i];
    }
}

// ---------- CSR build ----------
__global__ __launch_bounds__(256) void deg_count(const int* __restrict__ dst,
                                                 int* __restrict__ deg) {
    int e = blockIdx.x * blockDim.x + threadIdx.x;
    if (e < N_EDGES) atomicAdd(&deg[dst[e]], 1);
}

// exclusive scan of deg -> row_ptr[0..N] and woff[0..N); one block, 2 barriers.
__global__ __launch_bounds__(1024) void scan_kernel(const int* __restrict__ deg,
                                                    int* __restrict__ row_ptr,
                                                    int* __restrict__ woff) {
    constexpr int CHUNK = (N_NODES + 1023) / 1024;   // 49
    __shared__ int wsum[16];
    const int tid  = threadIdx.x;
    const int lane = tid & 63;
    const int wid  = tid >> 6;
    const int base = tid * CHUNK;
    // pass 1: serial chunk sum (contiguous reads)
    int sum = 0;
    for (int i = 0; i < CHUNK; ++i) {
        int idx = base + i;
        if (idx < N_NODES) sum += deg[idx];
    }
    // wave-inclusive scan via shfl_up
    int x = sum;
#pragma unroll
    for (int off = 1; off < 64; off <<= 1) {
        int t = __shfl_up(x, off, 64);
        if (lane >= off) x += t;
    }
    if (lane == 63) wsum[wid] = x;
    __syncthreads();
    int woffset = 0;
    for (int w = 0; w < wid; ++w) woffset += wsum[w];
    int run = woffset + (x - sum);   // exclusive prefix for this thread's chunk
    // pass 2: write prefixes
    if (tid == 0) row_ptr[0] = 0;
    for (int i = 0; i < CHUNK; ++i) {
        int idx = base + i;
        if (idx < N_NODES) {
            int v = deg[idx];
            woff[idx] = run;
            run += v;
            row_ptr[idx + 1] = run;
        }
    }
}

__global__ __launch_bounds__(256) void scatter_kernel(const int* __restrict__ src,
                                                      const int* __restrict__ dst,
                                                      int* __restrict__ woff,
                                                      int* __restrict__ csr_src) {
    int e = blockIdx.x * blockDim.x + threadIdx.x;
    if (e < N_EDGES) {
        int pos = atomicAdd(&woff[dst[e]], 1);
        csr_src[pos] = src[e];
    }
}

// ---------- fused dst-centric GATv2 layer (online softmax, no atomics) ----------
// MODE 0: ELU epilogue, write [N, H*D] row.  MODE 1 (D=8): head-mean, write [N, 8].
template<int D, int MODE>
__global__ __launch_bounds__(256) void fused_gat(const float* __restrict__ feat,
                                                 const int* __restrict__ row_ptr,
                                                 const int* __restrict__ csr_src,
                                                 const float* __restrict__ attn,
                                                 float* __restrict__ out) {
    constexpr int F   = HEADS * D;   // floats per row (128 or 32)
    constexpr int LPN = F / 4;       // lanes per node (32 or 8)
    constexpr int NPW = 64 / LPN;    // nodes per wave (2 or 8)
    const int lane = threadIdx.x & 63;
    const int wave = (blockIdx.x * blockDim.x + threadIdx.x) >> 6;
    const int sub  = lane / LPN;
    const int l    = lane % LPN;
    const int v    = wave * NPW + sub;
    if (v >= N_NODES) return;

    const float4 a4 = *(const float4*)(attn + (l * 4));
    const float4 fv = *(const float4*)(feat + (size_t)v * F + l * 4);

    float m = -INFINITY, s = 0.f;
    float4 acc = {0.f, 0.f, 0.f, 0.f};

    const int beg = row_ptr[v], end = row_ptr[v + 1];
    for (int j = beg; j < end; ++j) {
        const int u = csr_src[j];
        const float4 fu = *(const float4*)(feat + (size_t)u * F + l * 4);
        float t, sc = 0.f;
        t = fu.x + fv.x; t = t > 0.f ? t : t * NEG; sc += t * a4.x;
        t = fu.y + fv.y; t = t > 0.f ? t : t * NEG; sc += t * a4.y;
        t = fu.z + fv.z; t = t > 0.f ? t : t * NEG; sc += t * a4.z;
        t = fu.w + fv.w; t = t > 0.f ? t : t * NEG; sc += t * a4.w;
#pragma unroll
        for (int off = 1; off < D / 4; off <<= 1)
            sc += __shfl_xor(sc, off, 64);
        const float mnew  = fmaxf(m, sc);
        const float scale = expf(m - mnew);
        const float p     = expf(sc - mnew);
        s = s * scale + p;
        acc.x = acc.x * scale + fu.x * p;
        acc.y = acc.y * scale + fu.y * p;
        acc.z = acc.z * scale + fu.z * p;
        acc.w = acc.w * scale + fu.w * p;
        m = mnew;
    }

    const float inv = (s > 0.f) ? 1.f / s : 0.f;
    float4 r;
    r.x = acc.x * inv; r.y = acc.y * inv; r.z = acc.z * inv; r.w = acc.w * inv;
    if (MODE == 0) {
        r.x = r.x > 0.f ? r.x : expm1f(r.x);
        r.y = r.y > 0.f ? r.y : expm1f(r.y);
        r.z = r.z > 0.f ? r.z : expm1f(r.z);
        r.w = r.w > 0.f ? r.w : expm1f(r.w);
        *(float4*)(out + (size_t)v * F + l * 4) = r;
    } else {
        r.x += __shfl_xor(r.x, 2, 64); r.y += __shfl_xor(r.y, 2, 64);
        r.z += __shfl_xor(r.z, 2, 64); r.w += __shfl_xor(r.w, 2, 64);
        r.x += __shfl_xor(r.x, 4, 64); r.y += __shfl_xor(r.y, 4, 64);
        r.z += __shfl_xor(r.z, 4, 64); r.w += __shfl_xor(r.w, 4, 64);
        if (l < 2) {
            r.x *= 0.25f; r.y *= 0.25f; r.z *= 0.25f; r.w *= 0.25f;
            *(float4*)(out + (size_t)v * 8 + l * 4) = r;
        }
    }
}

extern "C" void kernel_launch(void* const* d_in, const int* in_sizes, int n_in,
                              void* d_out, int out_size, void* d_ws, size_t ws_size,
                              hipStream_t stream) {
    const float* features = (const float*)d_in[0];
    const float* W0 = (const float*)d_in[1];  const float* attn0 = (const float*)d_in[2];
    const float* W1 = (const float*)d_in[3];  const float* attn1 = (const float*)d_in[4];
    const float* W2 = (const float*)d_in[5];  const float* attn2 = (const float*)d_in[6];
    const float* W3 = (const float*)d_in[7];  const float* attn3 = (const float*)d_in[8];
    const int* src = (const int*)d_in[9];
    const int* dst = (const int*)d_in[10];
    float* out = (float*)d_out;

    // workspace layout
    float* bufA   = (float*)d_ws;                         // N*128 f
    float* feat   = bufA + (size_t)N_NODES * 128;         // N*128 f
    int* row_ptr  = (int*)(feat + (size_t)N_NODES * 128); // N+1
    int* woff     = row_ptr + (N_NODES + 1);              // N
    int* deg      = woff + N_NODES;                       // N
    int* csr_src  = deg + N_NODES;                        // E

    const int EBLK = (N_EDGES + 255) / 256;
    const int GB32 = (N_NODES + 31) / 32;    // gemm128 blocks
    const int GB16 = (N_NODES + 15) / 16;    // generic gemm blocks

    // ---- CSR build (graph static across layers) ----
    hipMemsetAsync(deg, 0, (size_t)N_NODES * 4, stream);
    deg_count<<<EBLK, 256, 0, stream>>>(dst, deg);
    scan_kernel<<<1, 1024, 0, stream>>>(deg, row_ptr, woff);
    scatter_kernel<<<EBLK, 256, 0, stream>>>(src, dst, woff, csr_src);

    const int FB32 = ((N_NODES + 1) / 2 * 64 + 255) / 256;   // D=32: 2 nodes/wave
    const int FB8  = ((N_NODES + 7) / 8 * 64 + 255) / 256;   // D=8:  8 nodes/wave

    // ---- layer 0 ----
    gemm128_kernel<16><<<GB32, 256, 0, stream>>>(features, W0, feat);
    fused_gat<32, 0><<<FB32, 256, 0, stream>>>(feat, row_ptr, csr_src, attn0, bufA);
    // ---- layer 1 ----
    gemm128_kernel<128><<<GB32, 256, 0, stream>>>(bufA, W1, feat);
    fused_gat<32, 0><<<FB32, 256, 0, stream>>>(feat, row_ptr, csr_src, attn1, bufA);
    // ---- layer 2 ----
    gemm128_kernel<128><<<GB32, 256, 0, stream>>>(bufA, W2, feat);
    fused_gat<32, 0><<<FB32, 256, 0, stream>>>(feat, row_ptr, csr_src, attn2, bufA);
    // ---- layer 3 (head-mean) ----
    gemm_kernel<128, 32><<<GB16, 128, 0, stream>>>(bufA, W3, feat);
    fused_gat<8, 1><<<FB8, 256, 0, stream>>>(feat, row_ptr, csr_src, attn3, out);
}

// Round 8
// 474.464 us; speedup vs baseline: 1.3536x; 1.3536x over previous
//
#include <hip/hip_runtime.h>
#include <hip/hip_bf16.h>
#include <math.h>

#define N_NODES 50000
#define N_EDGES 800000
#define HEADS 4
#define NEG 0.2f

#define SCAN_TILE 1024
#define SCAN_NB ((N_NODES + SCAN_TILE - 1) / SCAN_TILE)   // 49

// ---------- GEMM (FOUT=128): out[N,128] = h[N,FIN] @ W[FIN,128] ----------
template<int FIN>
__global__ __launch_bounds__(256) void gemm128_kernel(const float* __restrict__ h,
                                                      const float* __restrict__ W,
                                                      float* __restrict__ out) {
    constexpr int ROWS = 32;
    __shared__ float hs[ROWS][FIN];
    const int tid = threadIdx.x;
    const int rbase = blockIdx.x * ROWS;
    constexpr int VECS = ROWS * FIN / 4;
    for (int i = tid; i < VECS; i += 256) {
        int r = (i * 4) / FIN, c = (i * 4) % FIN;
        int gr = rbase + r;
        float4 v = {0.f, 0.f, 0.f, 0.f};
        if (gr < N_NODES) v = *(const float4*)(h + (size_t)gr * FIN + c);
        *(float4*)(&hs[r][c]) = v;
    }
    __syncthreads();
    const int c4 = (tid & 31) * 4;
    const int r0 = (tid >> 5) * 4;
    float a0[4] = {}, a1[4] = {}, a2[4] = {}, a3[4] = {};
    for (int k = 0; k < FIN; ++k) {
        const float4 w = *(const float4*)(W + k * 128 + c4);
        const float h0 = hs[r0 + 0][k], h1 = hs[r0 + 1][k];
        const float h2 = hs[r0 + 2][k], h3 = hs[r0 + 3][k];
        a0[0] += h0 * w.x; a0[1] += h0 * w.y; a0[2] += h0 * w.z; a0[3] += h0 * w.w;
        a1[0] += h1 * w.x; a1[1] += h1 * w.y; a1[2] += h1 * w.z; a1[3] += h1 * w.w;
        a2[0] += h2 * w.x; a2[1] += h2 * w.y; a2[2] += h2 * w.z; a2[3] += h2 * w.w;
        a3[0] += h3 * w.x; a3[1] += h3 * w.y; a3[2] += h3 * w.z; a3[3] += h3 * w.w;
    }
    float* rows[4] = {a0, a1, a2, a3};
#pragma unroll
    for (int i = 0; i < 4; ++i) {
        int gr = rbase + r0 + i;
        if (gr < N_NODES) {
            float4 v = {rows[i][0], rows[i][1], rows[i][2], rows[i][3]};
            *(float4*)(out + (size_t)gr * 128 + c4) = v;
        }
    }
}

// ---------- GEMM generic (FOUT=32 final layer) ----------
template<int FIN, int FOUT>
__global__ __launch_bounds__(128) void gemm_kernel(const float* __restrict__ h,
                                                   const float* __restrict__ W,
                                                   float* __restrict__ out) {
    constexpr int ROWS = 16;
    constexpr int SUBS = 128 / FOUT;
    constexpr int RPT  = ROWS / SUBS;
    __shared__ float hs[ROWS][FIN];
    const int tid = threadIdx.x;
    const int rbase = blockIdx.x * ROWS;
    for (int i = tid; i < ROWS * FIN; i += 128) {
        int r = i / FIN, c = i % FIN;
        int gr = rbase + r;
        hs[r][c] = (gr < N_NODES) ? h[(size_t)gr * FIN + c] : 0.f;
    }
    __syncthreads();
    const int col = tid % FOUT;
    const int sub = tid / FOUT;
    float acc[RPT];
#pragma unroll
    for (int i = 0; i < RPT; ++i) acc[i] = 0.f;
    for (int k = 0; k < FIN; ++k) {
        float w = W[k * FOUT + col];
#pragma unroll
        for (int i = 0; i < RPT; ++i) acc[i] += hs[sub * RPT + i][k] * w;
    }
#pragma unroll
    for (int i = 0; i < RPT; ++i) {
        int gr = rbase + sub * RPT + i;
        if (gr < N_NODES) out[(size_t)gr * FOUT + col] = acc[i];
    }
}

// ---------- CSR build ----------
__global__ __launch_bounds__(256) void deg_count(const int* __restrict__ dst,
                                                 int* __restrict__ deg) {
    int e = blockIdx.x * blockDim.x + threadIdx.x;
    if (e < N_EDGES) atomicAdd(&deg[dst[e]], 1);
}

// k1: per-tile reduce -> bsum[b]  (49 blocks x 256 threads, int4 coalesced)
__global__ __launch_bounds__(256) void scan_reduce(const int* __restrict__ deg,
                                                   int* __restrict__ bsum) {
    __shared__ int wtot[4];
    const int tid = threadIdx.x;
    const int base = blockIdx.x * SCAN_TILE + tid * 4;
    int s = 0;
    if (base < N_NODES) {   // N % 4 == 0 -> full int4 valid
        int4 v = *(const int4*)(deg + base);
        s = v.x + v.y + v.z + v.w;
    }
#pragma unroll
    for (int off = 1; off < 64; off <<= 1) s += __shfl_xor(s, off, 64);
    if ((tid & 63) == 0) wtot[tid >> 6] = s;
    __syncthreads();
    if (tid == 0) bsum[blockIdx.x] = wtot[0] + wtot[1] + wtot[2] + wtot[3];
}

// k2: tile scan + global offset -> row_ptr[0..N], woff[0..N)
__global__ __launch_bounds__(256) void scan_write(const int* __restrict__ deg,
                                                  const int* __restrict__ bsum,
                                                  int* __restrict__ row_ptr,
                                                  int* __restrict__ woff) {
    __shared__ int s_boff;
    __shared__ int wtot[4];
    const int tid  = threadIdx.x;
    const int lane = tid & 63;
    const int wid  = tid >> 6;
    const int b    = blockIdx.x;
    // block offset: sum of bsum[0..b) by wave 0 (SCAN_NB=49 <= 64)
    if (wid == 0) {
        int v = (lane < b) ? bsum[lane] : 0;
#pragma unroll
        for (int off = 1; off < 64; off <<= 1) v += __shfl_xor(v, off, 64);
        if (lane == 0) s_boff = v;
    }
    const int base = b * SCAN_TILE + tid * 4;
    int4 v = {0, 0, 0, 0};
    if (base < N_NODES) v = *(const int4*)(deg + base);
    const int t0 = v.x, t1 = t0 + v.y, t2 = t1 + v.z, t3 = t2 + v.w;
    // wave inclusive scan of thread sums
    int x = t3;
#pragma unroll
    for (int off = 1; off < 64; off <<= 1) {
        int t = __shfl_up(x, off, 64);
        if (lane >= off) x += t;
    }
    if (lane == 63) wtot[wid] = x;
    __syncthreads();
    int woffs = 0;
    for (int w = 0; w < wid; ++w) woffs += wtot[w];
    const int off0 = s_boff + woffs + (x - t3);   // exclusive prefix of this thread's 4
    if (base < N_NODES) {
        row_ptr[base + 1] = off0 + t0;  woff[base + 0] = off0 + t0 - v.x;
        row_ptr[base + 2] = off0 + t1;  woff[base + 1] = off0 + t1 - v.y;
        row_ptr[base + 3] = off0 + t2;  woff[base + 2] = off0 + t2 - v.z;
        row_ptr[base + 4] = off0 + t3;  woff[base + 3] = off0 + t3 - v.w;
    }
    if (b == 0 && tid == 0) row_ptr[0] = 0;
}

__global__ __launch_bounds__(256) void scatter_kernel(const int* __restrict__ src,
                                                      const int* __restrict__ dst,
                                                      int* __restrict__ woff,
                                                      int* __restrict__ csr_src) {
    int e = blockIdx.x * blockDim.x + threadIdx.x;
    if (e < N_EDGES) {
        int pos = atomicAdd(&woff[dst[e]], 1);
        csr_src[pos] = src[e];
    }
}

// ---------- fused dst-centric GATv2 layer (online softmax, 2x edge unroll) ----------
template<int D, int MODE>
__global__ __launch_bounds__(256) void fused_gat(const float* __restrict__ feat,
                                                 const int* __restrict__ row_ptr,
                                                 const int* __restrict__ csr_src,
                                                 const float* __restrict__ attn,
                                                 float* __restrict__ out) {
    constexpr int F   = HEADS * D;
    constexpr int LPN = F / 4;
    constexpr int NPW = 64 / LPN;
    const int lane = threadIdx.x & 63;
    const int wave = (blockIdx.x * blockDim.x + threadIdx.x) >> 6;
    const int sub  = lane / LPN;
    const int l    = lane % LPN;
    const int v    = wave * NPW + sub;
    if (v >= N_NODES) return;

    const float4 a4 = *(const float4*)(attn + (l * 4));
    const float4 fv = *(const float4*)(feat + (size_t)v * F + l * 4);

    float m = -INFINITY, s = 0.f;
    float4 acc = {0.f, 0.f, 0.f, 0.f};

    const int beg = row_ptr[v], end = row_ptr[v + 1];
    int j = beg;
    for (; j + 1 < end; j += 2) {
        const int u0 = csr_src[j], u1 = csr_src[j + 1];
        const float4 f0 = *(const float4*)(feat + (size_t)u0 * F + l * 4);
        const float4 f1 = *(const float4*)(feat + (size_t)u1 * F + l * 4);
        float t, sc0 = 0.f, sc1 = 0.f;
        t = f0.x + fv.x; t = t > 0.f ? t : t * NEG; sc0 += t * a4.x;
        t = f0.y + fv.y; t = t > 0.f ? t : t * NEG; sc0 += t * a4.y;
        t = f0.z + fv.z; t = t > 0.f ? t : t * NEG; sc0 += t * a4.z;
        t = f0.w + fv.w; t = t > 0.f ? t : t * NEG; sc0 += t * a4.w;
        t = f1.x + fv.x; t = t > 0.f ? t : t * NEG; sc1 += t * a4.x;
        t = f1.y + fv.y; t = t > 0.f ? t : t * NEG; sc1 += t * a4.y;
        t = f1.z + fv.z; t = t > 0.f ? t : t * NEG; sc1 += t * a4.z;
        t = f1.w + fv.w; t = t > 0.f ? t : t * NEG; sc1 += t * a4.w;
#pragma unroll
        for (int off = 1; off < D / 4; off <<= 1) {
            sc0 += __shfl_xor(sc0, off, 64);
            sc1 += __shfl_xor(sc1, off, 64);
        }
        const float mnew  = fmaxf(m, fmaxf(sc0, sc1));
        const float scale = expf(m - mnew);
        const float p0    = expf(sc0 - mnew);
        const float p1    = expf(sc1 - mnew);
        s = s * scale + p0 + p1;
        acc.x = acc.x * scale + f0.x * p0 + f1.x * p1;
        acc.y = acc.y * scale + f0.y * p0 + f1.y * p1;
        acc.z = acc.z * scale + f0.z * p0 + f1.z * p1;
        acc.w = acc.w * scale + f0.w * p0 + f1.w * p1;
        m = mnew;
    }
    if (j < end) {
        const int u = csr_src[j];
        const float4 fu = *(const float4*)(feat + (size_t)u * F + l * 4);
        float t, sc = 0.f;
        t = fu.x + fv.x; t = t > 0.f ? t : t * NEG; sc += t * a4.x;
        t = fu.y + fv.y; t = t > 0.f ? t : t * NEG; sc += t * a4.y;
        t = fu.z + fv.z; t = t > 0.f ? t : t * NEG; sc += t * a4.z;
        t = fu.w + fv.w; t = t > 0.f ? t : t * NEG; sc += t * a4.w;
#pragma unroll
        for (int off = 1; off < D / 4; off <<= 1)
            sc += __shfl_xor(sc, off, 64);
        const float mnew  = fmaxf(m, sc);
        const float scale = expf(m - mnew);
        const float p     = expf(sc - mnew);
        s = s * scale + p;
        acc.x = acc.x * scale + fu.x * p;
        acc.y = acc.y * scale + fu.y * p;
        acc.z = acc.z * scale + fu.z * p;
        acc.w = acc.w * scale + fu.w * p;
        m = mnew;
    }

    const float inv = (s > 0.f) ? 1.f / s : 0.f;
    float4 r;
    r.x = acc.x * inv; r.y = acc.y * inv; r.z = acc.z * inv; r.w = acc.w * inv;
    if (MODE == 0) {
        r.x = r.x > 0.f ? r.x : expm1f(r.x);
        r.y = r.y > 0.f ? r.y : expm1f(r.y);
        r.z = r.z > 0.f ? r.z : expm1f(r.z);
        r.w = r.w > 0.f ? r.w : expm1f(r.w);
        *(float4*)(out + (size_t)v * F + l * 4) = r;
    } else {
        r.x += __shfl_xor(r.x, 2, 64); r.y += __shfl_xor(r.y, 2, 64);
        r.z += __shfl_xor(r.z, 2, 64); r.w += __shfl_xor(r.w, 2, 64);
        r.x += __shfl_xor(r.x, 4, 64); r.y += __shfl_xor(r.y, 4, 64);
        r.z += __shfl_xor(r.z, 4, 64); r.w += __shfl_xor(r.w, 4, 64);
        if (l < 2) {
            r.x *= 0.25f; r.y *= 0.25f; r.z *= 0.25f; r.w *= 0.25f;
            *(float4*)(out + (size_t)v * 8 + l * 4) = r;
        }
    }
}

extern "C" void kernel_launch(void* const* d_in, const int* in_sizes, int n_in,
                              void* d_out, int out_size, void* d_ws, size_t ws_size,
                              hipStream_t stream) {
    const float* features = (const float*)d_in[0];
    const float* W0 = (const float*)d_in[1];  const float* attn0 = (const float*)d_in[2];
    const float* W1 = (const float*)d_in[3];  const float* attn1 = (const float*)d_in[4];
    const float* W2 = (const float*)d_in[5];  const float* attn2 = (const float*)d_in[6];
    const float* W3 = (const float*)d_in[7];  const float* attn3 = (const float*)d_in[8];
    const int* src = (const int*)d_in[9];
    const int* dst = (const int*)d_in[10];
    float* out = (float*)d_out;

    // workspace layout
    float* bufA   = (float*)d_ws;                         // N*128 f
    float* feat   = bufA + (size_t)N_NODES * 128;         // N*128 f
    int* row_ptr  = (int*)(feat + (size_t)N_NODES * 128); // N+1
    int* woff     = row_ptr + (N_NODES + 1);              // N
    int* deg      = woff + N_NODES;                       // N
    int* csr_src  = deg + N_NODES;                        // E
    int* bsum     = csr_src + N_EDGES;                    // SCAN_NB

    const int EBLK = (N_EDGES + 255) / 256;
    const int GB32 = (N_NODES + 31) / 32;
    const int GB16 = (N_NODES + 15) / 16;

    // ---- CSR build (graph static across layers) ----
    hipMemsetAsync(deg, 0, (size_t)N_NODES * 4, stream);
    deg_count<<<EBLK, 256, 0, stream>>>(dst, deg);
    scan_reduce<<<SCAN_NB, 256, 0, stream>>>(deg, bsum);
    scan_write<<<SCAN_NB, 256, 0, stream>>>(deg, bsum, row_ptr, woff);
    scatter_kernel<<<EBLK, 256, 0, stream>>>(src, dst, woff, csr_src);

    const int FB32 = ((N_NODES + 1) / 2 * 64 + 255) / 256;   // D=32: 2 nodes/wave
    const int FB8  = ((N_NODES + 7) / 8 * 64 + 255) / 256;   // D=8:  8 nodes/wave

    // ---- layer 0 ----
    gemm128_kernel<16><<<GB32, 256, 0, stream>>>(features, W0, feat);
    fused_gat<32, 0><<<FB32, 256, 0, stream>>>(feat, row_ptr, csr_src, attn0, bufA);
    // ---- layer 1 ----
    gemm128_kernel<128><<<GB32, 256, 0, stream>>>(bufA, W1, feat);
    fused_gat<32, 0><<<FB32, 256, 0, stream>>>(feat, row_ptr, csr_src, attn1, bufA);
    // ---- layer 2 ----
    gemm128_kernel<128><<<GB32, 256, 0, stream>>>(bufA, W2, feat);
    fused_gat<32, 0><<<FB32, 256, 0, stream>>>(feat, row_ptr, csr_src, attn2, bufA);
    // ---- layer 3 (head-mean) ----
    gemm_kernel<128, 32><<<GB16, 128, 0, stream>>>(bufA, W3, feat);
    fused_gat<8, 1><<<FB8, 256, 0, stream>>>(feat, row_ptr, csr_src, attn3, out);
}

// Round 9
// 467.942 us; speedup vs baseline: 1.3725x; 1.0139x over previous
//
#include <hip/hip_runtime.h>
#include <hip/hip_bf16.h>
#include <math.h>

#define N_NODES 50000
#define N_EDGES 800000
#define HEADS 4
#define NEG 0.2f

#define SCAN_TILE 1024
#define SCAN_NB ((N_NODES + SCAN_TILE - 1) / SCAN_TILE)   // 49

// ---------- GEMM (FOUT=128): out[N,128] = h[N,FIN] @ W[FIN,128] ----------
template<int FIN>
__global__ __launch_bounds__(256) void gemm128_kernel(const float* __restrict__ h,
                                                      const float* __restrict__ W,
                                                      float* __restrict__ out) {
    constexpr int ROWS = 32;
    __shared__ float hs[ROWS][FIN];
    const int tid = threadIdx.x;
    const int rbase = blockIdx.x * ROWS;
    constexpr int VECS = ROWS * FIN / 4;
    for (int i = tid; i < VECS; i += 256) {
        int r = (i * 4) / FIN, c = (i * 4) % FIN;
        int gr = rbase + r;
        float4 v = {0.f, 0.f, 0.f, 0.f};
        if (gr < N_NODES) v = *(const float4*)(h + (size_t)gr * FIN + c);
        *(float4*)(&hs[r][c]) = v;
    }
    __syncthreads();
    const int c4 = (tid & 31) * 4;
    const int r0 = (tid >> 5) * 4;
    float a0[4] = {}, a1[4] = {}, a2[4] = {}, a3[4] = {};
    for (int k = 0; k < FIN; ++k) {
        const float4 w = *(const float4*)(W + k * 128 + c4);
        const float h0 = hs[r0 + 0][k], h1 = hs[r0 + 1][k];
        const float h2 = hs[r0 + 2][k], h3 = hs[r0 + 3][k];
        a0[0] += h0 * w.x; a0[1] += h0 * w.y; a0[2] += h0 * w.z; a0[3] += h0 * w.w;
        a1[0] += h1 * w.x; a1[1] += h1 * w.y; a1[2] += h1 * w.z; a1[3] += h1 * w.w;
        a2[0] += h2 * w.x; a2[1] += h2 * w.y; a2[2] += h2 * w.z; a2[3] += h2 * w.w;
        a3[0] += h3 * w.x; a3[1] += h3 * w.y; a3[2] += h3 * w.z; a3[3] += h3 * w.w;
    }
    float* rows[4] = {a0, a1, a2, a3};
#pragma unroll
    for (int i = 0; i < 4; ++i) {
        int gr = rbase + r0 + i;
        if (gr < N_NODES) {
            float4 v = {rows[i][0], rows[i][1], rows[i][2], rows[i][3]};
            *(float4*)(out + (size_t)gr * 128 + c4) = v;
        }
    }
}

// ---------- GEMM generic (FOUT=32 final layer) ----------
template<int FIN, int FOUT>
__global__ __launch_bounds__(128) void gemm_kernel(const float* __restrict__ h,
                                                   const float* __restrict__ W,
                                                   float* __restrict__ out) {
    constexpr int ROWS = 16;
    constexpr int SUBS = 128 / FOUT;
    constexpr int RPT  = ROWS / SUBS;
    __shared__ float hs[ROWS][FIN];
    const int tid = threadIdx.x;
    const int rbase = blockIdx.x * ROWS;
    for (int i = tid; i < ROWS * FIN; i += 128) {
        int r = i / FIN, c = i % FIN;
        int gr = rbase + r;
        hs[r][c] = (gr < N_NODES) ? h[(size_t)gr * FIN + c] : 0.f;
    }
    __syncthreads();
    const int col = tid % FOUT;
    const int sub = tid / FOUT;
    float acc[RPT];
#pragma unroll
    for (int i = 0; i < RPT; ++i) acc[i] = 0.f;
    for (int k = 0; k < FIN; ++k) {
        float w = W[k * FOUT + col];
#pragma unroll
        for (int i = 0; i < RPT; ++i) acc[i] += hs[sub * RPT + i][k] * w;
    }
#pragma unroll
    for (int i = 0; i < RPT; ++i) {
        int gr = rbase + sub * RPT + i;
        if (gr < N_NODES) out[(size_t)gr * FOUT + col] = acc[i];
    }
}

// ---------- CSR build ----------
__global__ __launch_bounds__(256) void deg_count(const int* __restrict__ dst,
                                                 int* __restrict__ deg) {
    int e = blockIdx.x * blockDim.x + threadIdx.x;
    if (e < N_EDGES) atomicAdd(&deg[dst[e]], 1);
}

// k1: per-tile reduce -> bsum[b]  (49 blocks x 256 threads, int4 coalesced)
__global__ __launch_bounds__(256) void scan_reduce(const int* __restrict__ deg,
                                                   int* __restrict__ bsum) {
    __shared__ int wtot[4];
    const int tid = threadIdx.x;
    const int base = blockIdx.x * SCAN_TILE + tid * 4;
    int s = 0;
    if (base < N_NODES) {   // N % 4 == 0 -> full int4 valid
        int4 v = *(const int4*)(deg + base);
        s = v.x + v.y + v.z + v.w;
    }
#pragma unroll
    for (int off = 1; off < 64; off <<= 1) s += __shfl_xor(s, off, 64);
    if ((tid & 63) == 0) wtot[tid >> 6] = s;
    __syncthreads();
    if (tid == 0) bsum[blockIdx.x] = wtot[0] + wtot[1] + wtot[2] + wtot[3];
}

// k2: tile scan + global offset -> row_ptr[0..N], woff[0..N)
__global__ __launch_bounds__(256) void scan_write(const int* __restrict__ deg,
                                                  const int* __restrict__ bsum,
                                                  int* __restrict__ row_ptr,
                                                  int* __restrict__ woff) {
    __shared__ int s_boff;
    __shared__ int wtot[4];
    const int tid  = threadIdx.x;
    const int lane = tid & 63;
    const int wid  = tid >> 6;
    const int b    = blockIdx.x;
    // block offset: sum of bsum[0..b) by wave 0 (SCAN_NB=49 <= 64)
    if (wid == 0) {
        int v = (lane < b) ? bsum[lane] : 0;
#pragma unroll
        for (int off = 1; off < 64; off <<= 1) v += __shfl_xor(v, off, 64);
        if (lane == 0) s_boff = v;
    }
    const int base = b * SCAN_TILE + tid * 4;
    int4 v = {0, 0, 0, 0};
    if (base < N_NODES) v = *(const int4*)(deg + base);
    const int t0 = v.x, t1 = t0 + v.y, t2 = t1 + v.z, t3 = t2 + v.w;
    // wave inclusive scan of thread sums
    int x = t3;
#pragma unroll
    for (int off = 1; off < 64; off <<= 1) {
        int t = __shfl_up(x, off, 64);
        if (lane >= off) x += t;
    }
    if (lane == 63) wtot[wid] = x;
    __syncthreads();
    int woffs = 0;
    for (int w = 0; w < wid; ++w) woffs += wtot[w];
    const int off0 = s_boff + woffs + (x - t3);   // exclusive prefix of this thread's 4
    if (base < N_NODES) {
        row_ptr[base + 1] = off0 + t0;  woff[base + 0] = off0 + t0 - v.x;
        row_ptr[base + 2] = off0 + t1;  woff[base + 1] = off0 + t1 - v.y;
        row_ptr[base + 3] = off0 + t2;  woff[base + 2] = off0 + t2 - v.z;
        row_ptr[base + 4] = off0 + t3;  woff[base + 3] = off0 + t3 - v.w;
    }
    if (b == 0 && tid == 0) row_ptr[0] = 0;
}

__global__ __launch_bounds__(256) void scatter_kernel(const int* __restrict__ src,
                                                      const int* __restrict__ dst,
                                                      int* __restrict__ woff,
                                                      int* __restrict__ csr_src) {
    int e = blockIdx.x * blockDim.x + threadIdx.x;
    if (e < N_EDGES) {
        int pos = atomicAdd(&woff[dst[e]], 1);
        csr_src[pos] = src[e];
    }
}

// ---------- fused dst-centric GATv2 layer ----------
// Online softmax with defer-max (rescale only when max ratchets) + native exp.
template<int D, int MODE>
__global__ __launch_bounds__(256) void fused_gat(const float* __restrict__ feat,
                                                 const int* __restrict__ row_ptr,
                                                 const int* __restrict__ csr_src,
                                                 const float* __restrict__ attn,
                                                 float* __restrict__ out) {
    constexpr int F   = HEADS * D;
    constexpr int LPN = F / 4;
    constexpr int NPW = 64 / LPN;
    const int lane = threadIdx.x & 63;
    const int wave = (blockIdx.x * blockDim.x + threadIdx.x) >> 6;
    const int sub  = lane / LPN;
    const int l    = lane % LPN;
    const int v    = wave * NPW + sub;
    if (v >= N_NODES) return;

    const float4 a4 = *(const float4*)(attn + (l * 4));
    const float4 fv = *(const float4*)(feat + (size_t)v * F + l * 4);

    float m = -INFINITY, s = 0.f;
    float4 acc = {0.f, 0.f, 0.f, 0.f};

    const int beg = row_ptr[v], end = row_ptr[v + 1];
    int j = beg;
    for (; j + 1 < end; j += 2) {
        const int u0 = csr_src[j], u1 = csr_src[j + 1];
        const float4 f0 = *(const float4*)(feat + (size_t)u0 * F + l * 4);
        const float4 f1 = *(const float4*)(feat + (size_t)u1 * F + l * 4);
        float t, sc0 = 0.f, sc1 = 0.f;
        t = f0.x + fv.x; t = t > 0.f ? t : t * NEG; sc0 += t * a4.x;
        t = f0.y + fv.y; t = t > 0.f ? t : t * NEG; sc0 += t * a4.y;
        t = f0.z + fv.z; t = t > 0.f ? t : t * NEG; sc0 += t * a4.z;
        t = f0.w + fv.w; t = t > 0.f ? t : t * NEG; sc0 += t * a4.w;
        t = f1.x + fv.x; t = t > 0.f ? t : t * NEG; sc1 += t * a4.x;
        t = f1.y + fv.y; t = t > 0.f ? t : t * NEG; sc1 += t * a4.y;
        t = f1.z + fv.z; t = t > 0.f ? t : t * NEG; sc1 += t * a4.z;
        t = f1.w + fv.w; t = t > 0.f ? t : t * NEG; sc1 += t * a4.w;
#pragma unroll
        for (int off = 1; off < D / 4; off <<= 1) {
            sc0 += __shfl_xor(sc0, off, 64);
            sc1 += __shfl_xor(sc1, off, 64);
        }
        // defer-max: rescale only when the running max actually increases.
        const float scmax = fmaxf(sc0, sc1);
        if (scmax > m) {                 // lane-uniform per node (post-reduce)
            const float scale = __expf(m - scmax);   // m=-inf -> 0
            s *= scale;
            acc.x *= scale; acc.y *= scale; acc.z *= scale; acc.w *= scale;
            m = scmax;
        }
        const float p0 = __expf(sc0 - m);
        const float p1 = __expf(sc1 - m);
        s += p0 + p1;
        acc.x += f0.x * p0 + f1.x * p1;
        acc.y += f0.y * p0 + f1.y * p1;
        acc.z += f0.z * p0 + f1.z * p1;
        acc.w += f0.w * p0 + f1.w * p1;
    }
    if (j < end) {
        const int u = csr_src[j];
        const float4 fu = *(const float4*)(feat + (size_t)u * F + l * 4);
        float t, sc = 0.f;
        t = fu.x + fv.x; t = t > 0.f ? t : t * NEG; sc += t * a4.x;
        t = fu.y + fv.y; t = t > 0.f ? t : t * NEG; sc += t * a4.y;
        t = fu.z + fv.z; t = t > 0.f ? t : t * NEG; sc += t * a4.z;
        t = fu.w + fv.w; t = t > 0.f ? t : t * NEG; sc += t * a4.w;
#pragma unroll
        for (int off = 1; off < D / 4; off <<= 1)
            sc += __shfl_xor(sc, off, 64);
        if (sc > m) {
            const float scale = __expf(m - sc);
            s *= scale;
            acc.x *= scale; acc.y *= scale; acc.z *= scale; acc.w *= scale;
            m = sc;
        }
        const float p = __expf(sc - m);
        s += p;
        acc.x += fu.x * p;
        acc.y += fu.y * p;
        acc.z += fu.z * p;
        acc.w += fu.w * p;
    }

    const float inv = (s > 0.f) ? 1.f / s : 0.f;
    float4 r;
    r.x = acc.x * inv; r.y = acc.y * inv; r.z = acc.z * inv; r.w = acc.w * inv;
    if (MODE == 0) {
        r.x = r.x > 0.f ? r.x : expm1f(r.x);
        r.y = r.y > 0.f ? r.y : expm1f(r.y);
        r.z = r.z > 0.f ? r.z : expm1f(r.z);
        r.w = r.w > 0.f ? r.w : expm1f(r.w);
        *(float4*)(out + (size_t)v * F + l * 4) = r;
    } else {
        r.x += __shfl_xor(r.x, 2, 64); r.y += __shfl_xor(r.y, 2, 64);
        r.z += __shfl_xor(r.z, 2, 64); r.w += __shfl_xor(r.w, 2, 64);
        r.x += __shfl_xor(r.x, 4, 64); r.y += __shfl_xor(r.y, 4, 64);
        r.z += __shfl_xor(r.z, 4, 64); r.w += __shfl_xor(r.w, 4, 64);
        if (l < 2) {
            r.x *= 0.25f; r.y *= 0.25f; r.z *= 0.25f; r.w *= 0.25f;
            *(float4*)(out + (size_t)v * 8 + l * 4) = r;
        }
    }
}

extern "C" void kernel_launch(void* const* d_in, const int* in_sizes, int n_in,
                              void* d_out, int out_size, void* d_ws, size_t ws_size,
                              hipStream_t stream) {
    const float* features = (const float*)d_in[0];
    const float* W0 = (const float*)d_in[1];  const float* attn0 = (const float*)d_in[2];
    const float* W1 = (const float*)d_in[3];  const float* attn1 = (const float*)d_in[4];
    const float* W2 = (const float*)d_in[5];  const float* attn2 = (const float*)d_in[6];
    const float* W3 = (const float*)d_in[7];  const float* attn3 = (const float*)d_in[8];
    const int* src = (const int*)d_in[9];
    const int* dst = (const int*)d_in[10];
    float* out = (float*)d_out;

    // workspace layout
    float* bufA   = (float*)d_ws;                         // N*128 f
    float* feat   = bufA + (size_t)N_NODES * 128;         // N*128 f
    int* row_ptr  = (int*)(feat + (size_t)N_NODES * 128); // N+1
    int* woff     = row_ptr + (N_NODES + 1);              // N
    int* deg      = woff + N_NODES;                       // N
    int* csr_src  = deg + N_NODES;                        // E
    int* bsum     = csr_src + N_EDGES;                    // SCAN_NB

    const int EBLK = (N_EDGES + 255) / 256;
    const int GB32 = (N_NODES + 31) / 32;
    const int GB16 = (N_NODES + 15) / 16;

    // ---- CSR build (graph static across layers) ----
    hipMemsetAsync(deg, 0, (size_t)N_NODES * 4, stream);
    deg_count<<<EBLK, 256, 0, stream>>>(dst, deg);
    scan_reduce<<<SCAN_NB, 256, 0, stream>>>(deg, bsum);
    scan_write<<<SCAN_NB, 256, 0, stream>>>(deg, bsum, row_ptr, woff);
    scatter_kernel<<<EBLK, 256, 0, stream>>>(src, dst, woff, csr_src);

    const int FB32 = ((N_NODES + 1) / 2 * 64 + 255) / 256;   // D=32: 2 nodes/wave
    const int FB8  = ((N_NODES + 7) / 8 * 64 + 255) / 256;   // D=8:  8 nodes/wave

    // ---- layer 0 ----
    gemm128_kernel<16><<<GB32, 256, 0, stream>>>(features, W0, feat);
    fused_gat<32, 0><<<FB32, 256, 0, stream>>>(feat, row_ptr, csr_src, attn0, bufA);
    // ---- layer 1 ----
    gemm128_kernel<128><<<GB32, 256, 0, stream>>>(bufA, W1, feat);
    fused_gat<32, 0><<<FB32, 256, 0, stream>>>(feat, row_ptr, csr_src, attn1, bufA);
    // ---- layer 2 ----
    gemm128_kernel<128><<<GB32, 256, 0, stream>>>(bufA, W2, feat);
    fused_gat<32, 0><<<FB32, 256, 0, stream>>>(feat, row_ptr, csr_src, attn2, bufA);
    // ---- layer 3 (head-mean) ----
    gemm_kernel<128, 32><<<GB16, 128, 0, stream>>>(bufA, W3, feat);
    fused_gat<8, 1><<<FB8, 256, 0, stream>>>(feat, row_ptr, csr_src, attn3, out);
}

// Round 10
// 464.699 us; speedup vs baseline: 1.3821x; 1.0070x over previous
//
#include <hip/hip_runtime.h>
#include <hip/hip_bf16.h>
#include <math.h>

#define N_NODES 50000
#define N_EDGES 800000
#define HEADS 4
#define NEG 0.2f

#define SCAN_TILE 1024
#define SCAN_NB ((N_NODES + SCAN_TILE - 1) / SCAN_TILE)   // 49

// ---------- GEMM (FOUT=128): out[N,128] = h[N,FIN] @ W[FIN,128] ----------
template<int FIN>
__global__ __launch_bounds__(256) void gemm128_kernel(const float* __restrict__ h,
                                                      const float* __restrict__ W,
                                                      float* __restrict__ out) {
    constexpr int ROWS = 32;
    __shared__ float hs[ROWS][FIN];
    const int tid = threadIdx.x;
    const int rbase = blockIdx.x * ROWS;
    constexpr int VECS = ROWS * FIN / 4;
    for (int i = tid; i < VECS; i += 256) {
        int r = (i * 4) / FIN, c = (i * 4) % FIN;
        int gr = rbase + r;
        float4 v = {0.f, 0.f, 0.f, 0.f};
        if (gr < N_NODES) v = *(const float4*)(h + (size_t)gr * FIN + c);
        *(float4*)(&hs[r][c]) = v;
    }
    __syncthreads();
    const int c4 = (tid & 31) * 4;
    const int r0 = (tid >> 5) * 4;
    float a0[4] = {}, a1[4] = {}, a2[4] = {}, a3[4] = {};
    for (int k = 0; k < FIN; ++k) {
        const float4 w = *(const float4*)(W + k * 128 + c4);
        const float h0 = hs[r0 + 0][k], h1 = hs[r0 + 1][k];
        const float h2 = hs[r0 + 2][k], h3 = hs[r0 + 3][k];
        a0[0] += h0 * w.x; a0[1] += h0 * w.y; a0[2] += h0 * w.z; a0[3] += h0 * w.w;
        a1[0] += h1 * w.x; a1[1] += h1 * w.y; a1[2] += h1 * w.z; a1[3] += h1 * w.w;
        a2[0] += h2 * w.x; a2[1] += h2 * w.y; a2[2] += h2 * w.z; a2[3] += h2 * w.w;
        a3[0] += h3 * w.x; a3[1] += h3 * w.y; a3[2] += h3 * w.z; a3[3] += h3 * w.w;
    }
    float* rows[4] = {a0, a1, a2, a3};
#pragma unroll
    for (int i = 0; i < 4; ++i) {
        int gr = rbase + r0 + i;
        if (gr < N_NODES) {
            float4 v = {rows[i][0], rows[i][1], rows[i][2], rows[i][3]};
            *(float4*)(out + (size_t)gr * 128 + c4) = v;
        }
    }
}

// ---------- GEMM generic (FOUT=32 final layer) ----------
template<int FIN, int FOUT>
__global__ __launch_bounds__(128) void gemm_kernel(const float* __restrict__ h,
                                                   const float* __restrict__ W,
                                                   float* __restrict__ out) {
    constexpr int ROWS = 16;
    constexpr int SUBS = 128 / FOUT;
    constexpr int RPT  = ROWS / SUBS;
    __shared__ float hs[ROWS][FIN];
    const int tid = threadIdx.x;
    const int rbase = blockIdx.x * ROWS;
    for (int i = tid; i < ROWS * FIN; i += 128) {
        int r = i / FIN, c = i % FIN;
        int gr = rbase + r;
        hs[r][c] = (gr < N_NODES) ? h[(size_t)gr * FIN + c] : 0.f;
    }
    __syncthreads();
    const int col = tid % FOUT;
    const int sub = tid / FOUT;
    float acc[RPT];
#pragma unroll
    for (int i = 0; i < RPT; ++i) acc[i] = 0.f;
    for (int k = 0; k < FIN; ++k) {
        float w = W[k * FOUT + col];
#pragma unroll
        for (int i = 0; i < RPT; ++i) acc[i] += hs[sub * RPT + i][k] * w;
    }
#pragma unroll
    for (int i = 0; i < RPT; ++i) {
        int gr = rbase + sub * RPT + i;
        if (gr < N_NODES) out[(size_t)gr * FOUT + col] = acc[i];
    }
}

// ---------- CSR build ----------
__global__ __launch_bounds__(256) void deg_count(const int* __restrict__ dst,
                                                 int* __restrict__ deg) {
    int e = blockIdx.x * blockDim.x + threadIdx.x;
    if (e < N_EDGES) atomicAdd(&deg[dst[e]], 1);
}

// k1: per-tile reduce -> bsum[b]  (49 blocks x 256 threads, int4 coalesced)
__global__ __launch_bounds__(256) void scan_reduce(const int* __restrict__ deg,
                                                   int* __restrict__ bsum) {
    __shared__ int wtot[4];
    const int tid = threadIdx.x;
    const int base = blockIdx.x * SCAN_TILE + tid * 4;
    int s = 0;
    if (base < N_NODES) {   // N % 4 == 0 -> full int4 valid
        int4 v = *(const int4*)(deg + base);
        s = v.x + v.y + v.z + v.w;
    }
#pragma unroll
    for (int off = 1; off < 64; off <<= 1) s += __shfl_xor(s, off, 64);
    if ((tid & 63) == 0) wtot[tid >> 6] = s;
    __syncthreads();
    if (tid == 0) bsum[blockIdx.x] = wtot[0] + wtot[1] + wtot[2] + wtot[3];
}

// k2: tile scan + global offset -> row_ptr[0..N], woff[0..N)
__global__ __launch_bounds__(256) void scan_write(const int* __restrict__ deg,
                                                  const int* __restrict__ bsum,
                                                  int* __restrict__ row_ptr,
                                                  int* __restrict__ woff) {
    __shared__ int s_boff;
    __shared__ int wtot[4];
    const int tid  = threadIdx.x;
    const int lane = tid & 63;
    const int wid  = tid >> 6;
    const int b    = blockIdx.x;
    if (wid == 0) {
        int v = (lane < b) ? bsum[lane] : 0;
#pragma unroll
        for (int off = 1; off < 64; off <<= 1) v += __shfl_xor(v, off, 64);
        if (lane == 0) s_boff = v;
    }
    const int base = b * SCAN_TILE + tid * 4;
    int4 v = {0, 0, 0, 0};
    if (base < N_NODES) v = *(const int4*)(deg + base);
    const int t0 = v.x, t1 = t0 + v.y, t2 = t1 + v.z, t3 = t2 + v.w;
    int x = t3;
#pragma unroll
    for (int off = 1; off < 64; off <<= 1) {
        int t = __shfl_up(x, off, 64);
        if (lane >= off) x += t;
    }
    if (lane == 63) wtot[wid] = x;
    __syncthreads();
    int woffs = 0;
    for (int w = 0; w < wid; ++w) woffs += wtot[w];
    const int off0 = s_boff + woffs + (x - t3);
    if (base < N_NODES) {
        row_ptr[base + 1] = off0 + t0;  woff[base + 0] = off0 + t0 - v.x;
        row_ptr[base + 2] = off0 + t1;  woff[base + 1] = off0 + t1 - v.y;
        row_ptr[base + 3] = off0 + t2;  woff[base + 2] = off0 + t2 - v.z;
        row_ptr[base + 4] = off0 + t3;  woff[base + 3] = off0 + t3 - v.w;
    }
    if (b == 0 && tid == 0) row_ptr[0] = 0;
}

__global__ __launch_bounds__(256) void scatter_kernel(const int* __restrict__ src,
                                                      const int* __restrict__ dst,
                                                      int* __restrict__ woff,
                                                      int* __restrict__ csr_src) {
    int e = blockIdx.x * blockDim.x + threadIdx.x;
    if (e < N_EDGES) {
        int pos = atomicAdd(&woff[dst[e]], 1);
        csr_src[pos] = src[e];
    }
}

// ---------- fused dst-centric GATv2 layer ----------
// 4-edge software pipeline: 4 idx loads + 4 row gathers in flight per iteration.
// Online softmax with defer-max + native exp.
#define SCORE4(fu, sc)                                              \
    {                                                               \
        float t;                                                    \
        t = fu.x + fv.x; t = t > 0.f ? t : t * NEG; sc  = t * a4.x; \
        t = fu.y + fv.y; t = t > 0.f ? t : t * NEG; sc += t * a4.y; \
        t = fu.z + fv.z; t = t > 0.f ? t : t * NEG; sc += t * a4.z; \
        t = fu.w + fv.w; t = t > 0.f ? t : t * NEG; sc += t * a4.w; \
    }

template<int D, int MODE>
__global__ __launch_bounds__(256) void fused_gat(const float* __restrict__ feat,
                                                 const int* __restrict__ row_ptr,
                                                 const int* __restrict__ csr_src,
                                                 const float* __restrict__ attn,
                                                 float* __restrict__ out) {
    constexpr int F   = HEADS * D;
    constexpr int LPN = F / 4;
    constexpr int NPW = 64 / LPN;
    const int lane = threadIdx.x & 63;
    const int wave = (blockIdx.x * blockDim.x + threadIdx.x) >> 6;
    const int sub  = lane / LPN;
    const int l    = lane % LPN;
    const int v    = wave * NPW + sub;
    if (v >= N_NODES) return;

    const float4 a4 = *(const float4*)(attn + (l * 4));
    const float4 fv = *(const float4*)(feat + (size_t)v * F + l * 4);

    float m = -INFINITY, s = 0.f;
    float4 acc = {0.f, 0.f, 0.f, 0.f};

    const int beg = row_ptr[v], end = row_ptr[v + 1];
    int j = beg;
    for (; j + 3 < end; j += 4) {
        // 4 independent index loads, then 4 independent gathers -> 4 chains in flight
        const int u0 = csr_src[j + 0], u1 = csr_src[j + 1];
        const int u2 = csr_src[j + 2], u3 = csr_src[j + 3];
        const float4 f0 = *(const float4*)(feat + (size_t)u0 * F + l * 4);
        const float4 f1 = *(const float4*)(feat + (size_t)u1 * F + l * 4);
        const float4 f2 = *(const float4*)(feat + (size_t)u2 * F + l * 4);
        const float4 f3 = *(const float4*)(feat + (size_t)u3 * F + l * 4);
        float sc0, sc1, sc2, sc3;
        SCORE4(f0, sc0); SCORE4(f1, sc1); SCORE4(f2, sc2); SCORE4(f3, sc3);
#pragma unroll
        for (int off = 1; off < D / 4; off <<= 1) {
            sc0 += __shfl_xor(sc0, off, 64);
            sc1 += __shfl_xor(sc1, off, 64);
            sc2 += __shfl_xor(sc2, off, 64);
            sc3 += __shfl_xor(sc3, off, 64);
        }
        const float scmax = fmaxf(fmaxf(sc0, sc1), fmaxf(sc2, sc3));
        if (scmax > m) {                     // lane-uniform per node (post-reduce)
            const float scale = __expf(m - scmax);   // m=-inf -> 0
            s *= scale;
            acc.x *= scale; acc.y *= scale; acc.z *= scale; acc.w *= scale;
            m = scmax;
        }
        const float p0 = __expf(sc0 - m);
        const float p1 = __expf(sc1 - m);
        const float p2 = __expf(sc2 - m);
        const float p3 = __expf(sc3 - m);
        s += p0 + p1 + p2 + p3;
        acc.x += f0.x * p0 + f1.x * p1 + f2.x * p2 + f3.x * p3;
        acc.y += f0.y * p0 + f1.y * p1 + f2.y * p2 + f3.y * p3;
        acc.z += f0.z * p0 + f1.z * p1 + f2.z * p2 + f3.z * p3;
        acc.w += f0.w * p0 + f1.w * p1 + f2.w * p2 + f3.w * p3;
    }
    for (; j < end; ++j) {
        const int u = csr_src[j];
        const float4 fu = *(const float4*)(feat + (size_t)u * F + l * 4);
        float sc;
        SCORE4(fu, sc);
#pragma unroll
        for (int off = 1; off < D / 4; off <<= 1)
            sc += __shfl_xor(sc, off, 64);
        if (sc > m) {
            const float scale = __expf(m - sc);
            s *= scale;
            acc.x *= scale; acc.y *= scale; acc.z *= scale; acc.w *= scale;
            m = sc;
        }
        const float p = __expf(sc - m);
        s += p;
        acc.x += fu.x * p;
        acc.y += fu.y * p;
        acc.z += fu.z * p;
        acc.w += fu.w * p;
    }

    const float inv = (s > 0.f) ? 1.f / s : 0.f;
    float4 r;
    r.x = acc.x * inv; r.y = acc.y * inv; r.z = acc.z * inv; r.w = acc.w * inv;
    if (MODE == 0) {
        r.x = r.x > 0.f ? r.x : expm1f(r.x);
        r.y = r.y > 0.f ? r.y : expm1f(r.y);
        r.z = r.z > 0.f ? r.z : expm1f(r.z);
        r.w = r.w > 0.f ? r.w : expm1f(r.w);
        *(float4*)(out + (size_t)v * F + l * 4) = r;
    } else {
        r.x += __shfl_xor(r.x, 2, 64); r.y += __shfl_xor(r.y, 2, 64);
        r.z += __shfl_xor(r.z, 2, 64); r.w += __shfl_xor(r.w, 2, 64);
        r.x += __shfl_xor(r.x, 4, 64); r.y += __shfl_xor(r.y, 4, 64);
        r.z += __shfl_xor(r.z, 4, 64); r.w += __shfl_xor(r.w, 4, 64);
        if (l < 2) {
            r.x *= 0.25f; r.y *= 0.25f; r.z *= 0.25f; r.w *= 0.25f;
            *(float4*)(out + (size_t)v * 8 + l * 4) = r;
        }
    }
}

extern "C" void kernel_launch(void* const* d_in, const int* in_sizes, int n_in,
                              void* d_out, int out_size, void* d_ws, size_t ws_size,
                              hipStream_t stream) {
    const float* features = (const float*)d_in[0];
    const float* W0 = (const float*)d_in[1];  const float* attn0 = (const float*)d_in[2];
    const float* W1 = (const float*)d_in[3];  const float* attn1 = (const float*)d_in[4];
    const float* W2 = (const float*)d_in[5];  const float* attn2 = (const float*)d_in[6];
    const float* W3 = (const float*)d_in[7];  const float* attn3 = (const float*)d_in[8];
    const int* src = (const int*)d_in[9];
    const int* dst = (const int*)d_in[10];
    float* out = (float*)d_out;

    // workspace layout
    float* bufA   = (float*)d_ws;                         // N*128 f
    float* feat   = bufA + (size_t)N_NODES * 128;         // N*128 f
    int* row_ptr  = (int*)(feat + (size_t)N_NODES * 128); // N+1
    int* woff     = row_ptr + (N_NODES + 1);              // N
    int* deg      = woff + N_NODES;                       // N
    int* csr_src  = deg + N_NODES;                        // E
    int* bsum     = csr_src + N_EDGES;                    // SCAN_NB

    const int EBLK = (N_EDGES + 255) / 256;
    const int GB32 = (N_NODES + 31) / 32;
    const int GB16 = (N_NODES + 15) / 16;

    // ---- CSR build (graph static across layers) ----
    hipMemsetAsync(deg, 0, (size_t)N_NODES * 4, stream);
    deg_count<<<EBLK, 256, 0, stream>>>(dst, deg);
    scan_reduce<<<SCAN_NB, 256, 0, stream>>>(deg, bsum);
    scan_write<<<SCAN_NB, 256, 0, stream>>>(deg, bsum, row_ptr, woff);
    scatter_kernel<<<EBLK, 256, 0, stream>>>(src, dst, woff, csr_src);

    const int FB32 = ((N_NODES + 1) / 2 * 64 + 255) / 256;   // D=32: 2 nodes/wave
    const int FB8  = ((N_NODES + 7) / 8 * 64 + 255) / 256;   // D=8:  8 nodes/wave

    // ---- layer 0 ----
    gemm128_kernel<16><<<GB32, 256, 0, stream>>>(features, W0, feat);
    fused_gat<32, 0><<<FB32, 256, 0, stream>>>(feat, row_ptr, csr_src, attn0, bufA);
    // ---- layer 1 ----
    gemm128_kernel<128><<<GB32, 256, 0, stream>>>(bufA, W1, feat);
    fused_gat<32, 0><<<FB32, 256, 0, stream>>>(feat, row_ptr, csr_src, attn1, bufA);
    // ---- layer 2 ----
    gemm128_kernel<128><<<GB32, 256, 0, stream>>>(bufA, W2, feat);
    fused_gat<32, 0><<<FB32, 256, 0, stream>>>(feat, row_ptr, csr_src, attn2, bufA);
    // ---- layer 3 (head-mean) ----
    gemm_kernel<128, 32><<<GB16, 128, 0, stream>>>(bufA, W3, feat);
    fused_gat<8, 1><<<FB8, 256, 0, stream>>>(feat, row_ptr, csr_src, attn3, out);
}